// Round 2
// baseline (467.659 us; speedup 1.0000x reference)
//
#include <hip/hip_runtime.h>
#include <math.h>

#define NH   8
#define HW   32
#define LSEQ 2048
#define EMB  256
#define BB   2

typedef short bf16x8 __attribute__((ext_vector_type(8)));
typedef float f32x4  __attribute__((ext_vector_type(4)));
typedef unsigned short u16x4 __attribute__((ext_vector_type(4)));

__device__ __forceinline__ unsigned short f2bf(float x) {  // RNE
  union { float f; unsigned u; } v; v.f = x;
  unsigned r = v.u + 0x7fffu + ((v.u >> 16) & 1u);
  return (unsigned short)(r >> 16);
}
__device__ __forceinline__ float bf2f(unsigned short h) {
  union { float f; unsigned u; } v; v.u = ((unsigned)h) << 16;
  return v.f;
}
__device__ __forceinline__ void split2(float x, unsigned short& h, unsigned short& l) {
  h = f2bf(x);
  l = f2bf(x - bf2f(h));
}

// ---------------------------------------------------------------------------
// One-shot RNE hi/lo bf16 pre-split of X, Wp, Wo.  Bit-identical to the
// inline split2 the GEMMs used to do redundantly.
// ---------------------------------------------------------------------------
__global__ __launch_bounds__(256) void presplit(
    const float* __restrict__ X, const float* __restrict__ Wp,
    const float* __restrict__ Wo,
    unsigned short* __restrict__ Xh, unsigned short* __restrict__ Xl,
    unsigned short* __restrict__ Wph, unsigned short* __restrict__ Wpl,
    unsigned short* __restrict__ Woh, unsigned short* __restrict__ Wol) {
  const int NX = 4096 * 256, NP = 768 * 256, NO = 256 * 256;
  const int total4 = (NX + NP + NO) >> 2;
  int i4 = blockIdx.x * 256 + threadIdx.x;
  if (i4 >= total4) return;
  int e = i4 << 2;
  const float* src;
  unsigned short *dh, *dl;
  int off;
  if (e < NX)           { src = X;  dh = Xh;  dl = Xl;  off = e; }
  else if (e < NX + NP) { src = Wp; dh = Wph; dl = Wpl; off = e - NX; }
  else                  { src = Wo; dh = Woh; dl = Wol; off = e - NX - NP; }
  float4 v = *(const float4*)(src + off);
  u16x4 h, l;
  unsigned short hh, ll;
  split2(v.x, hh, ll); h[0] = hh; l[0] = ll;
  split2(v.y, hh, ll); h[1] = hh; l[1] = ll;
  split2(v.z, hh, ll); h[2] = hh; l[2] = ll;
  split2(v.w, hh, ll); h[3] = hh; l[3] = ll;
  *(u16x4*)(dh + off) = h;
  *(u16x4*)(dl + off) = l;
}

// ---------------------------------------------------------------------------
// QKV projection, split-bf16 MFMA, LDS-free, pre-split inputs.
// Block 256 thr = 4 waves stacked on m; wave = 16m x 64n; grid (12, 64).
// ---------------------------------------------------------------------------
__global__ __launch_bounds__(256, 4) void qkv_gemm(
    const unsigned short* __restrict__ Xh, const unsigned short* __restrict__ Xl,
    const unsigned short* __restrict__ Wph, const unsigned short* __restrict__ Wpl,
    unsigned short* __restrict__ Qh, unsigned short* __restrict__ Ql,
    unsigned short* __restrict__ Kh, unsigned short* __restrict__ Kl,
    unsigned short* __restrict__ Vth, unsigned short* __restrict__ Vtl) {
  const int t = threadIdx.x;
  const int w = t >> 6, lane = t & 63;
  const int col = lane & 15, quad = lane >> 4;
  const int m0 = blockIdx.y * 64 + w * 16;
  const int n0 = blockIdx.x * 64;
  const size_t xoff = (size_t)(m0 + col) * 256 + quad * 8;

  f32x4 acc[4];
#pragma unroll
  for (int nt = 0; nt < 4; ++nt) acc[nt] = (f32x4){0.f, 0.f, 0.f, 0.f};

#pragma unroll
  for (int es = 0; es < 8; ++es) {
    bf16x8 ah = *(const bf16x8*)(Xh + xoff + es * 32);
    bf16x8 al = *(const bf16x8*)(Xl + xoff + es * 32);
#pragma unroll
    for (int nt = 0; nt < 4; ++nt) {
      const size_t woff = (size_t)(n0 + nt * 16 + col) * 256 + es * 32 + quad * 8;
      bf16x8 bh = *(const bf16x8*)(Wph + woff);
      bf16x8 bl = *(const bf16x8*)(Wpl + woff);
      acc[nt] = __builtin_amdgcn_mfma_f32_16x16x32_bf16(ah, bh, acc[nt], 0, 0, 0);
      acc[nt] = __builtin_amdgcn_mfma_f32_16x16x32_bf16(ah, bl, acc[nt], 0, 0, 0);
      acc[nt] = __builtin_amdgcn_mfma_f32_16x16x32_bf16(al, bh, acc[nt], 0, 0, 0);
    }
  }

  const float qscale = 0.17677669529663687f;  // 32^-0.5
#pragma unroll
  for (int nt = 0; nt < 4; ++nt) {
    const int f = n0 + nt * 16 + col;
    const int hd = f / 96, r0 = f - hd * 96;
#pragma unroll
    for (int r = 0; r < 4; ++r) {
      const int m = m0 + quad * 4 + r;
      const int bbv = m >> 11, ll = m & 2047;
      float v = acc[nt][r];
      unsigned short hi, lo;
      if (r0 < 64) {
        float sv = (r0 < 32) ? v * qscale : v;
        split2(sv, hi, lo);
        size_t idx = ((size_t)(bbv * NH + hd) * LSEQ + ll) * HW + (r0 & 31);
        if (r0 < 32) { Qh[idx] = hi; Ql[idx] = lo; }
        else         { Kh[idx] = hi; Kl[idx] = lo; }
      } else {
        split2(v, hi, lo);
        size_t idx = ((size_t)(bbv * NH + hd) * HW + (r0 - 64)) * LSEQ + ll;
        Vth[idx] = hi; Vtl[idx] = lo;
      }
    }
  }
}

// ---------------------------------------------------------------------------
// MFMA flash attention with pair bias, FULL k-range per block (no k-split).
// Grid 512: (qtile 128 x b 2) x hh 2, hh-sibling (x^8) on same XCD for bias
// line share.  Block 512 thr = 8 waves = 4 heads x 2 wks; q-tile 16 rows;
// 32 iters of 64-k tiles (wks waves split each tile 32/32, merged at end).
// Bias tile staged to LDS [h][q][k] (reg-prefetched 1 tile ahead) -> MFMA
// C-initializer.  P-bounce packs hi|lo in one dword.  V loads issued after
// softmax (short live range).  Final output normalized (1/l) and written as
// split bf16 hi/lo -> out_gemm is a pure GEMM.  LDS 36.9KB -> 2 blocks/CU.
// ---------------------------------------------------------------------------
__global__ __launch_bounds__(512, 4) void attn(
    const unsigned short* __restrict__ Qh, const unsigned short* __restrict__ Ql,
    const unsigned short* __restrict__ Kh, const unsigned short* __restrict__ Kl,
    const unsigned short* __restrict__ Vth, const unsigned short* __restrict__ Vtl,
    const float* __restrict__ Bias,
    unsigned short* __restrict__ Yh, unsigned short* __restrict__ Yl) {
  __shared__ __attribute__((aligned(16))) float Bst[4 * 16 * 72];     // 18.4KB
  __shared__ __attribute__((aligned(16))) unsigned Pbuf[8 * 576];     // 18.4KB
  const int t = threadIdx.x;
  const int w = t >> 6, lane = t & 63;
  const int col = lane & 15, quad = lane >> 4;
  const int head = w >> 1, wks = w & 1;
  const int x = blockIdx.x;
  const int p = ((x >> 4) << 3) | (x & 7);   // [0,256)
  const int hh = (x >> 3) & 1;
  const int b = p & 1;
  const int q0g = (p >> 1) * 16;
  const int hg = hh * 4 + head;

  const size_t bhoff = (size_t)(b * NH + hg) * LSEQ * HW;
  const unsigned short* Qhp = Qh + bhoff;
  const unsigned short* Qlp = Ql + bhoff;
  const unsigned short* Khp = Kh + bhoff;
  const unsigned short* Klp = Kl + bhoff;
  const unsigned short* Vhp = Vth + bhoff;
  const unsigned short* Vlp = Vtl + bhoff;
  unsigned* Pw = &Pbuf[w * 576];

  // Q B-frag (q=col, c=quad*8+j)
  bf16x8 Qbh, Qbl;
  {
    size_t off = (size_t)(q0g + col) * HW + quad * 8;
    Qbh = *(const bf16x8*)(Qhp + off);
    Qbl = *(const bf16x8*)(Qlp + off);
  }

  f32x4 o[2];
#pragma unroll
  for (int ct = 0; ct < 2; ++ct) o[ct] = (f32x4){0.f, 0.f, 0.f, 0.f};
  float m_i = -1e30f, l_i = 0.f;

  // staging index (thread-uniform per u): q = u*8 + w, k = lane
  const int sq = w, sk = lane;
  // prefetch bias tile 0
  float4 bsr[2];
#pragma unroll
  for (int u = 0; u < 2; ++u)
    bsr[u] = *(const float4*)&Bias[(((size_t)(b * LSEQ + q0g + u * 8 + sq)) * LSEQ +
                                    sk) * NH + hh * 4];

#pragma unroll 1
  for (int it = 0; it < 32; ++it) {
    __syncthreads();  // prior reads of Bst done
    // K loads (A-frag: k=col) -- issued first, L2 latency hides under staging
    const int kw = it * 64 + wks * 32;
    bf16x8 Kah[2], Kal[2];
#pragma unroll
    for (int kt = 0; kt < 2; ++kt) {
      size_t off = (size_t)(kw + kt * 16 + col) * HW + quad * 8;
      Kah[kt] = *(const bf16x8*)(Khp + off);
      Kal[kt] = *(const bf16x8*)(Klp + off);
    }
#pragma unroll
    for (int u = 0; u < 2; ++u) {
      const int qq = u * 8 + sq;
      Bst[0 * 1152 + qq * 72 + sk] = bsr[u].x;
      Bst[1 * 1152 + qq * 72 + sk] = bsr[u].y;
      Bst[2 * 1152 + qq * 72 + sk] = bsr[u].z;
      Bst[3 * 1152 + qq * 72 + sk] = bsr[u].w;
    }
    if (it < 31) {
#pragma unroll
      for (int u = 0; u < 2; ++u)
        bsr[u] = *(const float4*)&Bias[(((size_t)(b * LSEQ + q0g + u * 8 + sq)) * LSEQ +
                                        (it + 1) * 64 + sk) * NH + hh * 4];
    }
    __syncthreads();  // Bst visible

    // S^T = K.Q^T with C initialized to bias (bias[q=col][k=quad*4+r])
    f32x4 s[2];
#pragma unroll
    for (int kt = 0; kt < 2; ++kt) {
      f32x4 a = *(const f32x4*)&Bst[head * 1152 + col * 72 +
                                    wks * 32 + kt * 16 + quad * 4];
      a = __builtin_amdgcn_mfma_f32_16x16x32_bf16(Kah[kt], Qbh, a, 0, 0, 0);
      a = __builtin_amdgcn_mfma_f32_16x16x32_bf16(Kah[kt], Qbl, a, 0, 0, 0);
      a = __builtin_amdgcn_mfma_f32_16x16x32_bf16(Kal[kt], Qbh, a, 0, 0, 0);
      s[kt] = a;
    }

    // online softmax (row = q = col; spread over quads via xor 16/32)
    {
      float mx = s[0][0];
#pragma unroll
      for (int r = 1; r < 4; ++r) mx = fmaxf(mx, s[0][r]);
#pragma unroll
      for (int r = 0; r < 4; ++r) mx = fmaxf(mx, s[1][r]);
      mx = fmaxf(mx, __shfl_xor(mx, 16, 64));
      mx = fmaxf(mx, __shfl_xor(mx, 32, 64));
      float mnew = fmaxf(m_i, mx);
      float al = __expf(m_i - mnew);
      float ps = 0.f;
#pragma unroll
      for (int kt = 0; kt < 2; ++kt)
#pragma unroll
        for (int r = 0; r < 4; ++r) {
          float pv = __expf(s[kt][r] - mnew);
          s[kt][r] = pv;
          ps += pv;
        }
      ps += __shfl_xor(ps, 16, 64);
      ps += __shfl_xor(ps, 32, 64);
      l_i = l_i * al + ps;
      m_i = mnew;
#pragma unroll
      for (int ct = 0; ct < 2; ++ct)
#pragma unroll
        for (int r = 0; r < 4; ++r) o[ct][r] *= al;
    }

    // V loads (A-frag: c=col) -- needed only for PV; short live range
    bf16x8 Vah[2], Val[2];
#pragma unroll
    for (int ct = 0; ct < 2; ++ct) {
      size_t off = (size_t)(ct * 16 + col) * LSEQ + kw + quad * 8;
      Vah[ct] = *(const bf16x8*)(Vhp + off);
      Val[ct] = *(const bf16x8*)(Vlp + off);
    }

    // P bounce: split hi/lo BEFORE store, pack into one dword per element.
#pragma unroll
    for (int kt = 0; kt < 2; ++kt)
#pragma unroll
      for (int r = 0; r < 4; ++r) {
        unsigned short hi, lo; split2(s[kt][r], hi, lo);
        Pw[(kt * 16 + quad * 4 + r) * 17 + col] =
            (unsigned)hi | ((unsigned)lo << 16);
      }
    bf16x8 Pbh, Pbl;
#pragma unroll
    for (int j = 0; j < 8; ++j) {
      unsigned d = Pw[(quad * 8 + j) * 17 + col];
      Pbh[j] = (short)(d & 0xffffu);
      Pbl[j] = (short)(d >> 16);
    }
    // O^T += V^T . P^T
#pragma unroll
    for (int ct = 0; ct < 2; ++ct) {
      f32x4 a = o[ct];
      a = __builtin_amdgcn_mfma_f32_16x16x32_bf16(Vah[ct], Pbh, a, 0, 0, 0);
      a = __builtin_amdgcn_mfma_f32_16x16x32_bf16(Vah[ct], Pbl, a, 0, 0, 0);
      a = __builtin_amdgcn_mfma_f32_16x16x32_bf16(Val[ct], Pbh, a, 0, 0, 0);
      o[ct] = a;
    }
  }

  // ---- merge the two wks waves of each head; write final bf16 hi/lo ----
  __syncthreads();
  float* Pwf = (float*)Pw;
  if (wks == 1) {
#pragma unroll
    for (int ct = 0; ct < 2; ++ct)
#pragma unroll
      for (int r = 0; r < 4; ++r)
        Pwf[(ct * 16 + quad * 4 + r) * 17 + col] = o[ct][r];
    if (quad == 0) {
      Pwf[544 + col] = m_i;
      Pwf[560 + col] = l_i;
    }
  }
  __syncthreads();
  if (wks == 0) {
    const float* Pp = Pwf + 576;  // partner (same head, wks=1)
    float m2 = Pp[544 + col];
    float l2 = Pp[560 + col];
    float mm = fmaxf(m_i, m2);
    float a1 = __expf(m_i - mm);
    float a2 = __expf(m2 - mm);
    float inv = 1.0f / (l_i * a1 + l2 * a2);
    a1 *= inv; a2 *= inv;
    const size_t row = (size_t)(b * LSEQ + q0g + col);
#pragma unroll
    for (int ct = 0; ct < 2; ++ct) {
      u16x4 rh, rl;
#pragma unroll
      for (int r = 0; r < 4; ++r) {
        float res = o[ct][r] * a1 + Pp[(ct * 16 + quad * 4 + r) * 17 + col] * a2;
        unsigned short hi, lo; split2(res, hi, lo);
        rh[r] = hi; rl[r] = lo;
      }
      size_t idx = row * EMB + hg * HW + ct * 16 + quad * 4;
      *(u16x4*)&Yh[idx] = rh;
      *(u16x4*)&Yl[idx] = rl;
    }
  }
}

// ---------------------------------------------------------------------------
// Output projection: pure split-bf16 GEMM (Y already merged/normalized and
// pre-split by attn).  Block 256 = 4 waves on m; wave 16m x 64n; grid (4,64).
// ---------------------------------------------------------------------------
__global__ __launch_bounds__(256, 4) void out_gemm(
    const unsigned short* __restrict__ Yh, const unsigned short* __restrict__ Yl,
    const unsigned short* __restrict__ Woh, const unsigned short* __restrict__ Wol,
    const float* __restrict__ bo, float* __restrict__ Out) {
  const int t = threadIdx.x;
  const int w = t >> 6, lane = t & 63;
  const int col = lane & 15, quad = lane >> 4;
  const int m0 = blockIdx.y * 64 + w * 16;
  const int n0 = blockIdx.x * 64;
  const size_t yoff = (size_t)(m0 + col) * 256 + quad * 8;

  f32x4 acc[4];
#pragma unroll
  for (int nt = 0; nt < 4; ++nt) acc[nt] = (f32x4){0.f, 0.f, 0.f, 0.f};

#pragma unroll
  for (int es = 0; es < 8; ++es) {
    bf16x8 ah = *(const bf16x8*)(Yh + yoff + es * 32);
    bf16x8 al = *(const bf16x8*)(Yl + yoff + es * 32);
#pragma unroll
    for (int nt = 0; nt < 4; ++nt) {
      const size_t woff = (size_t)(n0 + nt * 16 + col) * 256 + es * 32 + quad * 8;
      bf16x8 bh = *(const bf16x8*)(Woh + woff);
      bf16x8 bl = *(const bf16x8*)(Wol + woff);
      acc[nt] = __builtin_amdgcn_mfma_f32_16x16x32_bf16(ah, bh, acc[nt], 0, 0, 0);
      acc[nt] = __builtin_amdgcn_mfma_f32_16x16x32_bf16(ah, bl, acc[nt], 0, 0, 0);
      acc[nt] = __builtin_amdgcn_mfma_f32_16x16x32_bf16(al, bh, acc[nt], 0, 0, 0);
    }
  }
#pragma unroll
  for (int nt = 0; nt < 4; ++nt) {
    const int f = n0 + nt * 16 + col;
    const float bias_o = bo[f];
#pragma unroll
    for (int r = 0; r < 4; ++r)
      Out[(size_t)(m0 + quad * 4 + r) * 256 + f] = acc[nt][r] + bias_o;
  }
}

extern "C" void kernel_launch(void* const* d_in, const int* in_sizes, int n_in,
                              void* d_out, int out_size, void* d_ws, size_t ws_size,
                              hipStream_t stream) {
  const float* X    = (const float*)d_in[0];
  const float* Bias = (const float*)d_in[1];
  const float* Wp   = (const float*)d_in[2];
  const float* Wo   = (const float*)d_in[3];
  const float* bo   = (const float*)d_in[4];
  float* Out = (float*)d_out;

  const size_t qkv_elems = (size_t)BB * NH * LSEQ * HW;  // 1,048,576
  unsigned short* Qh  = (unsigned short*)d_ws;
  unsigned short* Ql  = Qh + qkv_elems;
  unsigned short* Kh  = Ql + qkv_elems;
  unsigned short* Kl  = Kh + qkv_elems;
  unsigned short* Vth = Kl + qkv_elems;
  unsigned short* Vtl = Vth + qkv_elems;
  unsigned short* Yh  = Vtl + qkv_elems;                 // [4096][256] bf16 hi
  unsigned short* Yl  = Yh + (size_t)4096 * 256;         // [4096][256] bf16 lo
  unsigned short* Xh  = Yl + (size_t)4096 * 256;
  unsigned short* Xl  = Xh  + (size_t)4096 * 256;
  unsigned short* Wph = Xl  + (size_t)4096 * 256;
  unsigned short* Wpl = Wph + (size_t)768 * 256;
  unsigned short* Woh = Wpl + (size_t)768 * 256;
  unsigned short* Wol = Woh + (size_t)256 * 256;

  presplit<<<dim3(1280), 256, 0, stream>>>(X, Wp, Wo, Xh, Xl, Wph, Wpl, Woh, Wol);
  qkv_gemm<<<dim3(12, 64), 256, 0, stream>>>(Xh, Xl, Wph, Wpl, Qh, Ql, Kh, Kl, Vth, Vtl);
  attn<<<dim3(512), 512, 0, stream>>>(Qh, Ql, Kh, Kl, Vth, Vtl, Bias, Yh, Yl);
  out_gemm<<<dim3(4, 64), 256, 0, stream>>>(Yh, Yl, Woh, Wol, bo, Out);
}